// Round 9
// baseline (246.809 us; speedup 1.0000x reference)
//
#include <hip/hip_runtime.h>

// MN neuron forward sim: T=1000 sequential steps, 64x512 independent chains.
// Round 9 (resubmit; previous bench died to container infra, not the kernel):
// R7b base + BRANCH-SPECULATED recurrence (chain 13 -> ~7 ops/step).
// Eliminated theories: store drains (R4), producer RT (R5), issue/literals
// (R7b, -6cyc), LDS read latency (R8: guaranteed 2-step read-ahead = null).
// Standing theory: loop-carried dependent-VALU latency ~14 cyc/edge with one
// wave/SIMD (m07's ~4cyc is a TLP-hidden throughput figure). 13 deps x 14.5
// = 189 cyc/step == observed R2/R4. Fix: compute BOTH spike/no-spike
// successor candidates for every chain value BEFORE the compare resolves,
// select after: select(sb, f(a), f(b)) == f(select(sb, a, b)) bit-exactly
// when f uses identical ops on both branches.
// Carried pre-select state: V1,T1 (integrated, pre-reset), tm=max(T1,TR),
// i1d,i2d (decayed, pre-reset), i1r,i2r (reset values), sb (prev decision).
// Exact constant folds on the spike branch (selected only when prev spiked):
//   e_sp = VR-EL = +0.0f (equal-value f32 sub); g_sp = G*+0.0 = +0.0f;
//   s_sp = rs-+0.0f = rs (exact for all finite/inf rs).
// Anti-refold: every select has branch-distinct operand pairs (Vn=V1+dn vs
// Vs=VR+dsp, T1n=T1+d2n vs T1s=tm+d2s, dfn=Vn-T1n vs dfs=Vs-T1s...) so
// InstCombine cannot sink the select back into a shared op.
// CORRECTNESS: taken-path op sequence is bit-identical to the reference for
// every step (both-branch compute + bitwise cndmask; discarded branch cannot
// propagate). absmax must stay 0.0.
// Producer/consumer structure, barriers, SGPR consts, LDS spike staging +
// producer NT flush: verbatim from verified R7b (~76.5us).

#define T_STEPS 1000
#define B_DIM 64
#define N_DIM 512
#define BN (B_DIM * N_DIM)   // 32768

#define K_CHUNK 20
#define NCHUNK (T_STEPS / K_CHUNK)   // 50

typedef const __attribute__((address_space(1))) void* gp_t;
typedef __attribute__((address_space(3))) void* lp_t;
typedef float f32x4 __attribute__((ext_vector_type(4)));

__device__ __forceinline__ void raw_barrier() {
    asm volatile("s_barrier" ::: "memory");
}

struct Consts {
    float k200, k20, kDT, kEL, kG, kTINF, kB, kR1, kR2, kTR;
};

// One speculated step. sbp = spike decision of the PREVIOUS step.
// Returns this step's spike value; updates all carried pre-select state.
__device__ __forceinline__ float mn_step_spec(
    float xt, float lin, float av, float A1v, float A2v, const Consts& K,
    float& V1, float& T1, float& tm_,
    float& i1d, float& i1r, float& i2d, float& i2r, bool& sbp)
{
#pragma clang fp contract(off)
    // ---- candidate pairs over sbp (no dependence on this step's compare) ----
    float a1n = i1d - (K.k200 * i1d) * K.kDT;   // decay(no-spike i1)
    float a1s = i1r - (K.k200 * i1r) * K.kDT;   // decay(spike-reset i1)
    float a2n = i2d - (K.k20  * i2d) * K.kDT;
    float a2s = i2r - (K.k20  * i2r) * K.kDT;
    float p   = lin * xt;
    float qn  = p + a1n;
    float qs  = p + a1s;
    float rn  = qn + a2n;
    float rs  = qs + a2s;
    float en  = V1 - K.kEL;        // e_sp = VR-EL = +0.0f exactly (folded)
    float gn  = K.kG * en;         // g_sp = +0.0f exactly (folded)
    float sn  = rn - gn;           // s_sp = rs - +0.0f = rs exactly (folded)
    float dn  = K.kDT * sn;
    float dsp = K.kDT * rs;
    float Vn  = V1 + dn;
    float Vs  = K.kEL + dsp;       // VR == EL (same bits)
    float e2n = Vn - K.kEL;
    float e2s = Vs - K.kEL;
    float un  = av * e2n;
    float us  = av * e2s;
    float wn  = T1  - K.kTINF;
    float ws  = tm_ - K.kTINF;
    float bn  = K.kB * wn;
    float bs  = K.kB * ws;
    float s2n = un - bn;
    float s2s = us - bs;
    float d2n = K.kDT * s2n;
    float d2s = K.kDT * s2s;
    float T1n = T1  + d2n;
    float T1s = tm_ + d2s;
    float dfn = Vn - T1n;
    float dfs = Vs - T1s;
    // ---- resolve previous step's selection (1 cndmask after prev cmp) ----
    float diff = sbp ? dfs : dfn;
    V1  = sbp ? Vs  : Vn;          // integrated V at this step (pre-reset)
    T1  = sbp ? T1s : T1n;         // integrated Thr at this step (pre-reset)
    i1d = sbp ? a1s : a1n;         // decayed i1 at this step (pre-reset)
    i2d = sbp ? a2s : a2n;
    // ---- this step's spike decision ----
    bool  sb  = diff > 0.0f;
    float spk = sb ? 1.0f : 0.0f;
    sbp = sb;
    // ---- post-compute spike-branch sources for the NEXT step ----
    tm_ = fmaxf(T1, K.kTR);        // ref: tm = max(Thr1_pre-reset, TR)
    i1r = (K.kR1 * i1d) + A1v;     // ref: from decayed (pre-reset) i1
    i2r = (K.kR2 * i2d) + A2v;
    return spk;
}

__global__ __launch_bounds__(128, 1) void mn_neuron_kernel(
    const float* __restrict__ x, const float* __restrict__ linear,
    const float* __restrict__ a, const float* __restrict__ A1,
    const float* __restrict__ A2, float* __restrict__ out)
{
#pragma clang fp contract(off)
    __shared__ float xb_buf[2][K_CHUNK][64];   // staged x
    __shared__ float sb_buf[2][K_CHUNK][64];   // staged spikes

    const int lane = threadIdx.x & 63;
    const int wid  = threadIdx.x >> 6;     // 0 = consumer, 1 = producer
    const int blk  = blockIdx.x;

    if (wid == 1) {
        // ---- producer: x staging + spike flush (verbatim R7b) ----
        const float* pl = x + (size_t)(lane >> 4) * BN
                            + (size_t)blk * 64 + (size_t)(lane & 15) * 4;
        float* outp = out + (size_t)blk * 64;

        auto issue = [&](int k) {   // chunk k's 5 width-16 loads -> xb[k&1]
            const float* pc = pl + (size_t)(k * K_CHUNK) * BN;
            float* dst = &xb_buf[k & 1][0][0];
#pragma unroll
            for (int s5 = 0; s5 < K_CHUNK / 4; ++s5) {
                __builtin_amdgcn_global_load_lds(
                    (gp_t)(pc + (size_t)(s5 * 4) * BN),
                    (lp_t)(dst + s5 * 4 * 64), 16, 0, 0);
            }
        };

        const int r0 = lane >> 4;          // 0..3
        const int c4 = (lane & 15) * 4;    // 0,4,..,60
        auto flush = [&](int k) {          // spikes of chunk k -> HBM
            const int kb = k & 1;
#pragma unroll
            for (int pz = 0; pz < K_CHUNK / 4; ++pz) {
                const int row = pz * 4 + r0;
                const f32x4 v = *reinterpret_cast<const f32x4*>(
                    &sb_buf[kb][row][c4]);                       // ds_read_b128
                f32x4* dp = reinterpret_cast<f32x4*>(
                    outp + (size_t)(k * K_CHUNK + row) * BN + c4);
                __builtin_nontemporal_store(v, dp);              // dwordx4 nt
            }
        };

        issue(0);
        asm volatile("s_waitcnt vmcnt(0)" ::: "memory");
        raw_barrier();                                           // B0

        for (int c = 0; c < NCHUNK; ++c) {
            if (c + 1 < NCHUNK) issue(c + 1);
            if (c >= 1)         flush(c - 1);
            asm volatile("s_waitcnt vmcnt(0) lgkmcnt(0)" ::: "memory");
            raw_barrier();                                       // B(c+1)
        }
        flush(NCHUNK - 1);   // after final barrier; consumer exited
    } else {
        // ---- consumer: speculated recurrence ----
        const int idx = blk * 64 + lane;       // b*N + n
        const int n   = idx & (N_DIM - 1);

        const float lin = linear[n];
        const float av  = a[n];
        const float A1v = A1[n];
        const float A2v = A2[n];

        Consts K = {200.0f, 20.0f, 0.01f, -0.07f,
                    45.24007797241211f, -0.05f, 12.77495288848877f,
                    0.3858567178249359f, -1.1421641111373901f, -0.06f};
        asm volatile("" : "+s"(K.k200), "+s"(K.k20), "+s"(K.kDT),
                          "+s"(K.kEL), "+s"(K.kG), "+s"(K.kTINF),
                          "+s"(K.kB), "+s"(K.kR1), "+s"(K.kR2), "+s"(K.kTR));

        // fictional step -1: no spike; selected state == reference init.
        float V1  = K.kEL;               // -> e_ns(0) = EL-EL, as ref
        float T1  = K.kTINF;
        float tm_ = fmaxf(K.kTINF, K.kTR);
        float i1d = 0.0f;
        float i1r = (K.kR1 * 0.0f) + A1v;   // discarded unless sbp (false)
        float i2d = 0.0f;
        float i2r = (K.kR2 * 0.0f) + A2v;
        bool  sbp = false;

        asm volatile("s_setprio 1" ::: "memory");
        raw_barrier();                                           // B0

        for (int c = 0; c < NCHUNK; ++c) {
            const float* src = &xb_buf[c & 1][0][lane];
            float*       dst = &sb_buf[c & 1][0][lane];
#pragma unroll
            for (int j = 0; j < K_CHUNK; ++j) {
                float xt  = src[j * 64];                 // ds_read_b32 imm
                float spk = mn_step_spec(xt, lin, av, A1v, A2v, K,
                                         V1, T1, tm_, i1d, i1r, i2d, i2r, sbp);
                dst[j * 64] = spk;                       // ds_write_b32 imm
            }
            asm volatile("s_waitcnt lgkmcnt(0)" ::: "memory");
            raw_barrier();                                       // B(c+1)
        }
    }
}

extern "C" void kernel_launch(void* const* d_in, const int* in_sizes, int n_in,
                              void* d_out, int out_size, void* d_ws, size_t ws_size,
                              hipStream_t stream) {
    const float* x      = (const float*)d_in[0];
    const float* linear = (const float*)d_in[1];
    const float* a      = (const float*)d_in[2];
    const float* A1     = (const float*)d_in[3];
    const float* A2     = (const float*)d_in[4];
    float* out = (float*)d_out;

    // 512 blocks x 128 threads (1 consumer wave + 1 producer wave each)
    mn_neuron_kernel<<<BN / 64, 128, 0, stream>>>(x, linear, a, A1, A2, out);
}